// Round 1
// baseline (914.618 us; speedup 1.0000x reference)
//
#include <hip/hip_runtime.h>

#define N_NODES 100000
#define N_EDGES 1600000
#define C 128
#define NCLS 40

// ---------------- CSR build ----------------

__global__ void deg_hist_k(const int* __restrict__ dst, int* __restrict__ deg) {
  int e = blockIdx.x * 256 + threadIdx.x;
  if (e < N_EDGES) atomicAdd(&deg[dst[e]], 1);
}

__global__ void scan_reduce_k(const int* __restrict__ deg, int* __restrict__ partials) {
  int b = blockIdx.x, tid = threadIdx.x;
  int base = b * 1024;
  int s = 0;
#pragma unroll
  for (int j = 0; j < 4; j++) {
    int i = base + tid + j * 256;
    if (i < N_NODES) s += deg[i];
  }
  for (int d = 32; d > 0; d >>= 1) s += __shfl_down(s, d, 64);
  __shared__ int wsum[4];
  if ((tid & 63) == 0) wsum[tid >> 6] = s;
  __syncthreads();
  if (tid == 0) partials[b] = wsum[0] + wsum[1] + wsum[2] + wsum[3];
}

__global__ void scan_partials_k(const int* __restrict__ partials, int* __restrict__ pscan, int nblk) {
  if (threadIdx.x == 0 && blockIdx.x == 0) {
    int run = 0;
    for (int b = 0; b < nblk; b++) { pscan[b] = run; run += partials[b]; }
  }
}

__global__ void scan_apply_k(const int* __restrict__ deg, const int* __restrict__ pscan,
                             int* __restrict__ rp, int* __restrict__ cursor) {
  int b = blockIdx.x, tid = threadIdx.x;
  int base = b * 1024 + tid * 4;
  int v[4];
#pragma unroll
  for (int j = 0; j < 4; j++) { int i = base + j; v[j] = (i < N_NODES) ? deg[i] : 0; }
  int tsum = v[0] + v[1] + v[2] + v[3];
  int lane = tid & 63, wid = tid >> 6;
  int inc = tsum;
  for (int d = 1; d < 64; d <<= 1) { int y = __shfl_up(inc, d, 64); if (lane >= d) inc += y; }
  __shared__ int wsum[4];
  if (lane == 63) wsum[wid] = inc;
  __syncthreads();
  int woff = 0;
  for (int w = 0; w < wid; w++) woff += wsum[w];
  int ex = woff + inc - tsum + pscan[b];
#pragma unroll
  for (int j = 0; j < 4; j++) {
    int i = base + j;
    if (i < N_NODES) {
      rp[i] = ex;
      cursor[i] = ex;
      if (i == N_NODES - 1) rp[N_NODES] = ex + v[j];
      ex += v[j];
    }
  }
}

__global__ void scatter_k(const int* __restrict__ src, const int* __restrict__ dst,
                          int* __restrict__ cursor, int* __restrict__ csr) {
  int e = blockIdx.x * 256 + threadIdx.x;
  if (e < N_EDGES) {
    int d = dst[e];
    int p = atomicAdd(&cursor[d], 1);
    csr[p] = src[e];
  }
}

// ---------------- mean aggregation (1 wave per node) ----------------

__global__ __launch_bounds__(256) void agg_mean_k(const float* __restrict__ feat,
    const int* __restrict__ rp, const int* __restrict__ csr, float* __restrict__ out) {
  int node = blockIdx.x * 4 + (threadIdx.x >> 6);
  int lane = threadIdx.x & 63;
  int beg = rp[node], end = rp[node + 1];
  float a0 = 0.f, a1 = 0.f;
  for (int j = beg; j < end; j++) {
    int s = csr[j];
    float2 v = *(const float2*)(feat + (size_t)s * C + lane * 2);
    a0 += v.x; a1 += v.y;
  }
  float inv = 1.0f / fmaxf((float)(end - beg), 1.0f);
  *(float2*)(out + (size_t)node * C + lane * 2) = make_float2(a0 * inv, a1 * inv);
}

// ---------------- fused SAGE layer: relu(Xs@Ws + Xn@Wn + b) ----------------

__device__ __forceinline__ void gemm_phase(const float* A, const float* __restrict__ W,
                                           int r0, int c0, float acc[4][4]) {
#pragma unroll 2
  for (int k = 0; k < C; k += 4) {
    float4 a[4];
#pragma unroll
    for (int i = 0; i < 4; i++) a[i] = *(const float4*)(A + (r0 + i) * C + k);
    float4 w[4];
#pragma unroll
    for (int j = 0; j < 4; j++) w[j] = *(const float4*)(W + (size_t)(k + j) * C + c0);
#pragma unroll
    for (int i = 0; i < 4; i++) {
      acc[i][0] += a[i].x * w[0].x + a[i].y * w[1].x + a[i].z * w[2].x + a[i].w * w[3].x;
      acc[i][1] += a[i].x * w[0].y + a[i].y * w[1].y + a[i].z * w[2].y + a[i].w * w[3].y;
      acc[i][2] += a[i].x * w[0].z + a[i].y * w[1].z + a[i].z * w[2].z + a[i].w * w[3].z;
      acc[i][3] += a[i].x * w[0].w + a[i].y * w[1].w + a[i].z * w[2].w + a[i].w * w[3].w;
    }
  }
}

// NOTE: Xn and out may alias (same 32-row tile read fully before written) -> no __restrict__.
__global__ __launch_bounds__(256) void sage_gemm_k(
    const float* __restrict__ Xs, const float* Xn,
    const float* __restrict__ Ws, const float* __restrict__ Wn,
    const float* __restrict__ bias, float* out) {
  __shared__ float As[32][C];
  __shared__ float An[32][C];
  int tid = threadIdx.x;
  size_t row0 = (size_t)blockIdx.x * 32;
  const float4* Xs4 = (const float4*)(Xs + row0 * C);
  const float4* Xn4 = (const float4*)(Xn + row0 * C);
  float4* As4 = (float4*)As;
  float4* An4 = (float4*)An;
#pragma unroll
  for (int i = 0; i < 4; i++) {
    As4[i * 256 + tid] = Xs4[i * 256 + tid];
    An4[i * 256 + tid] = Xn4[i * 256 + tid];
  }
  __syncthreads();
  int tn = tid & 31, tm = tid >> 5;
  int c0 = tn * 4, r0 = tm * 4;
  float acc[4][4] = {};
  gemm_phase(&As[0][0], Ws, r0, c0, acc);
  gemm_phase(&An[0][0], Wn, r0, c0, acc);
  float4 b4 = *(const float4*)(bias + c0);
#pragma unroll
  for (int i = 0; i < 4; i++) {
    float4 o;
    o.x = fmaxf(acc[i][0] + b4.x, 0.f);
    o.y = fmaxf(acc[i][1] + b4.y, 0.f);
    o.z = fmaxf(acc[i][2] + b4.z, 0.f);
    o.w = fmaxf(acc[i][3] + b4.w, 0.f);
    *(float4*)(out + (row0 + r0 + i) * C + c0) = o;
  }
}

// ---------------- classifier: h2 @ W_cls + b_cls ----------------

__global__ __launch_bounds__(256) void classifier_k(const float* __restrict__ h,
    const float* __restrict__ Wc, const float* __restrict__ bc, float* __restrict__ out) {
  __shared__ float Hs[64][C + 4];
  __shared__ float WcT[NCLS][C + 4];
  __shared__ float bs[NCLS];
  int tid = threadIdx.x;
  size_t row0 = (size_t)blockIdx.x * 64;
  for (int idx = tid; idx < C * NCLS; idx += 256) {
    int k = idx / NCLS, c = idx - k * NCLS;
    WcT[c][k] = Wc[idx];
  }
  if (tid < NCLS) bs[tid] = bc[tid];
  for (int f = tid; f < 64 * 32; f += 256) {
    int r = f >> 5, c4 = f & 31;
    size_t gr = row0 + r;
    float4 v = make_float4(0.f, 0.f, 0.f, 0.f);
    if (gr < N_NODES) v = *(const float4*)(h + gr * C + c4 * 4);
    *(float4*)&Hs[r][c4 * 4] = v;
  }
  __syncthreads();
  int r = tid >> 2, cg = tid & 3;
  float acc[10] = {};
#pragma unroll 2
  for (int k = 0; k < C; k += 4) {
    float4 a = *(const float4*)&Hs[r][k];
#pragma unroll
    for (int cc = 0; cc < 10; cc++) {
      float4 wv = *(const float4*)&WcT[cg * 10 + cc][k];
      acc[cc] += a.x * wv.x + a.y * wv.y + a.z * wv.z + a.w * wv.w;
    }
  }
  size_t gr = row0 + r;
  if (gr < N_NODES) {
#pragma unroll
    for (int cc = 0; cc < 10; cc++)
      out[gr * NCLS + cg * 10 + cc] = acc[cc] + bs[cg * 10 + cc];
  }
}

// ---------------- launch ----------------

extern "C" void kernel_launch(void* const* d_in, const int* in_sizes, int n_in,
                              void* d_out, int out_size, void* d_ws, size_t ws_size,
                              hipStream_t stream) {
  (void)in_sizes; (void)n_in; (void)out_size; (void)ws_size;
  const float* x   = (const float*)d_in[0];
  const int*   ei  = (const int*)d_in[1];
  const float* Ws1 = (const float*)d_in[2];
  const float* Wn1 = (const float*)d_in[3];
  const float* b1  = (const float*)d_in[4];
  const float* Ws2 = (const float*)d_in[5];
  const float* Wn2 = (const float*)d_in[6];
  const float* b2  = (const float*)d_in[7];
  const float* Wc  = (const float*)d_in[8];
  const float* bc  = (const float*)d_in[9];
  const int* src = ei;
  const int* dst = ei + N_EDGES;

  char* ws = (char*)d_ws;
  size_t off = 0;
  auto alloc = [&](size_t bytes) {
    void* p = ws + off;
    off = (off + bytes + 255) & ~(size_t)255;
    return p;
  };
  int*   deg      = (int*)alloc((size_t)N_NODES * 4);
  int*   rp       = (int*)alloc((size_t)(N_NODES + 1) * 4);
  int*   cursor   = (int*)alloc((size_t)N_NODES * 4);
  int*   partials = (int*)alloc(128 * 4);
  int*   pscan    = (int*)alloc(128 * 4);
  int*   csr      = (int*)alloc((size_t)N_EDGES * 4);
  float* bufA     = (float*)alloc((size_t)N_NODES * C * 4);
  float* bufB     = (float*)alloc((size_t)N_NODES * C * 4);
  float* outf     = (float*)d_out;

  hipMemsetAsync(deg, 0, (size_t)N_NODES * 4, stream);
  deg_hist_k<<<(N_EDGES + 255) / 256, 256, 0, stream>>>(dst, deg);
  int nblk = (N_NODES + 1023) / 1024;  // 98
  scan_reduce_k<<<nblk, 256, 0, stream>>>(deg, partials);
  scan_partials_k<<<1, 64, 0, stream>>>(partials, pscan, nblk);
  scan_apply_k<<<nblk, 256, 0, stream>>>(deg, pscan, rp, cursor);
  scatter_k<<<(N_EDGES + 255) / 256, 256, 0, stream>>>(src, dst, cursor, csr);

  // layer 1
  agg_mean_k<<<N_NODES / 4, 256, 0, stream>>>(x, rp, csr, bufA);
  sage_gemm_k<<<N_NODES / 32, 256, 0, stream>>>(x, bufA, Ws1, Wn1, b1, bufB);
  // layer 2 (h2 overwrites bufA tile-locally: safe, reads precede writes per block)
  agg_mean_k<<<N_NODES / 4, 256, 0, stream>>>(bufB, rp, csr, bufA);
  sage_gemm_k<<<N_NODES / 32, 256, 0, stream>>>(bufB, bufA, Ws2, Wn2, b2, bufA);
  // classifier
  classifier_k<<<(N_NODES + 63) / 64, 256, 0, stream>>>(bufA, Wc, bc, outf);
}

// Round 2
// 614.138 us; speedup vs baseline: 1.4893x; 1.4893x over previous
//
#include <hip/hip_runtime.h>

#define N_NODES 100000
#define N_EDGES 1600000
#define C 128
#define NCLS 40

typedef _Float16 half8 __attribute__((ext_vector_type(8)));
typedef _Float16 h2f __attribute__((ext_vector_type(2)));
typedef float f32x4 __attribute__((ext_vector_type(4)));

// ---------------- CSR build ----------------

__global__ void deg_hist_k(const int* __restrict__ dst, int* __restrict__ deg) {
  int e = blockIdx.x * 256 + threadIdx.x;
  if (e < N_EDGES) atomicAdd(&deg[dst[e]], 1);
}

__global__ void scan_reduce_k(const int* __restrict__ deg, int* __restrict__ partials) {
  int b = blockIdx.x, tid = threadIdx.x;
  int base = b * 1024;
  int s = 0;
#pragma unroll
  for (int j = 0; j < 4; j++) {
    int i = base + tid + j * 256;
    if (i < N_NODES) s += deg[i];
  }
  for (int d = 32; d > 0; d >>= 1) s += __shfl_down(s, d, 64);
  __shared__ int wsum[4];
  if ((tid & 63) == 0) wsum[tid >> 6] = s;
  __syncthreads();
  if (tid == 0) partials[b] = wsum[0] + wsum[1] + wsum[2] + wsum[3];
}

__global__ void scan_partials_k(const int* __restrict__ partials, int* __restrict__ pscan, int nblk) {
  if (threadIdx.x == 0 && blockIdx.x == 0) {
    int run = 0;
    for (int b = 0; b < nblk; b++) { pscan[b] = run; run += partials[b]; }
  }
}

__global__ void scan_apply_k(const int* __restrict__ deg, const int* __restrict__ pscan,
                             int* __restrict__ rp, int* __restrict__ cursor) {
  int b = blockIdx.x, tid = threadIdx.x;
  int base = b * 1024 + tid * 4;
  int v[4];
#pragma unroll
  for (int j = 0; j < 4; j++) { int i = base + j; v[j] = (i < N_NODES) ? deg[i] : 0; }
  int tsum = v[0] + v[1] + v[2] + v[3];
  int lane = tid & 63, wid = tid >> 6;
  int inc = tsum;
  for (int d = 1; d < 64; d <<= 1) { int y = __shfl_up(inc, d, 64); if (lane >= d) inc += y; }
  __shared__ int wsum[4];
  if (lane == 63) wsum[wid] = inc;
  __syncthreads();
  int woff = 0;
  for (int w = 0; w < wid; w++) woff += wsum[w];
  int ex = woff + inc - tsum + pscan[b];
#pragma unroll
  for (int j = 0; j < 4; j++) {
    int i = base + j;
    if (i < N_NODES) {
      rp[i] = ex;
      cursor[i] = ex;
      if (i == N_NODES - 1) rp[N_NODES] = ex + v[j];
      ex += v[j];
    }
  }
}

__global__ void scatter_k(const int* __restrict__ src, const int* __restrict__ dst,
                          int* __restrict__ cursor, int* __restrict__ csr) {
  int e = blockIdx.x * 256 + threadIdx.x;
  if (e < N_EDGES) {
    int d = dst[e];
    int p = atomicAdd(&cursor[d], 1);
    csr[p] = src[e];
  }
}

// ---------------- fp32 -> fp16 convert ----------------

__global__ __launch_bounds__(256) void f32_to_f16_k(const float* __restrict__ in,
                                                    _Float16* __restrict__ out) {
  int i = blockIdx.x * 256 + threadIdx.x;  // one thread = 8 elements
  float4 v0 = *(const float4*)(in + (size_t)i * 8);
  float4 v1 = *(const float4*)(in + (size_t)i * 8 + 4);
  half8 o;
  o[0] = (_Float16)v0.x; o[1] = (_Float16)v0.y; o[2] = (_Float16)v0.z; o[3] = (_Float16)v0.w;
  o[4] = (_Float16)v1.x; o[5] = (_Float16)v1.y; o[6] = (_Float16)v1.z; o[7] = (_Float16)v1.w;
  *(half8*)(out + (size_t)i * 8) = o;
}

// WT[n][k] = f16( k<128 ? Ws[k][n] : Wn[k-128][n] ), n in [0,128), k in [0,256)
__global__ void build_wt_k(const float* __restrict__ Ws, const float* __restrict__ Wn,
                           _Float16* __restrict__ WT) {
  int n = blockIdx.x, k = threadIdx.x;
  float v = (k < 128) ? Ws[k * 128 + n] : Wn[(k - 128) * 128 + n];
  WT[n * 256 + k] = (_Float16)v;
}

// ---------------- mean aggregation (1 wave per node, f16 feats, unroll 4) ----------------

__global__ __launch_bounds__(256) void agg_mean_h_k(const _Float16* __restrict__ feat,
    const int* __restrict__ rp, const int* __restrict__ csr, _Float16* __restrict__ out) {
  int node = blockIdx.x * 4 + (threadIdx.x >> 6);
  int lane = threadIdx.x & 63;
  int beg = rp[node], end = rp[node + 1];
  float s0 = 0.f, s1 = 0.f, t0 = 0.f, t1 = 0.f;
  int j = beg;
  for (; j + 3 < end; j += 4) {
    int n0 = csr[j], n1 = csr[j + 1], n2 = csr[j + 2], n3 = csr[j + 3];
    h2f p0 = *(const h2f*)(feat + (size_t)n0 * C + lane * 2);
    h2f p1 = *(const h2f*)(feat + (size_t)n1 * C + lane * 2);
    h2f p2 = *(const h2f*)(feat + (size_t)n2 * C + lane * 2);
    h2f p3 = *(const h2f*)(feat + (size_t)n3 * C + lane * 2);
    s0 += (float)p0.x + (float)p1.x;
    s1 += (float)p0.y + (float)p1.y;
    t0 += (float)p2.x + (float)p3.x;
    t1 += (float)p2.y + (float)p3.y;
  }
  for (; j < end; j++) {
    int n0 = csr[j];
    h2f p0 = *(const h2f*)(feat + (size_t)n0 * C + lane * 2);
    s0 += (float)p0.x;
    s1 += (float)p0.y;
  }
  float inv = 1.0f / fmaxf((float)(end - beg), 1.0f);
  h2f o;
  o.x = (_Float16)((s0 + t0) * inv);
  o.y = (_Float16)((s1 + t1) * inv);
  *(h2f*)(out + (size_t)node * C + lane * 2) = o;
}

// ---------------- fused SAGE layer via MFMA f16 ----------------
// out = relu( [Xs|Xn] @ WT^T + b )   (WT is [128 cols][256 k], f16)
// block = 4 waves; tile 32 rows x 128 cols; wave tile 16x64.

__global__ __launch_bounds__(256) void sage_gemm_h_k(
    const _Float16* __restrict__ Xs, const _Float16* __restrict__ Xn,
    const _Float16* __restrict__ WT, const float* __restrict__ bias,
    _Float16* __restrict__ out) {
  __shared__ _Float16 lds_out[4][16][72];
  int tid = threadIdx.x;
  int lane = tid & 63, wid = tid >> 6;
  int wm = wid >> 1, wn = wid & 1;
  int lr = lane & 15, lk = lane >> 4;
  size_t rowbase = (size_t)blockIdx.x * 32 + wm * 16;
  int n0 = wn * 64;

  // preload all 8 A fragments (K=256 over [Xs|Xn]) -> 8 loads in flight
  half8 a[8];
#pragma unroll
  for (int ks = 0; ks < 8; ks++) {
    const _Float16* Ap = (ks < 4)
        ? Xs + (rowbase + lr) * C + ks * 32 + lk * 8
        : Xn + (rowbase + lr) * C + (ks - 4) * 32 + lk * 8;
    a[ks] = *(const half8*)Ap;
  }

  f32x4 acc[4] = {};
#pragma unroll
  for (int ks = 0; ks < 8; ks++) {
#pragma unroll
    for (int nf = 0; nf < 4; nf++) {
      half8 b = *(const half8*)(WT + (size_t)(n0 + nf * 16 + lr) * 256 + ks * 32 + lk * 8);
      acc[nf] = __builtin_amdgcn_mfma_f32_16x16x32_f16(a[ks], b, acc[nf], 0, 0, 0);
    }
  }

  // epilogue: bias + relu -> LDS (f16) -> coalesced 16B stores
#pragma unroll
  for (int nf = 0; nf < 4; nf++) {
    float bcol = bias[n0 + nf * 16 + lr];
#pragma unroll
    for (int r = 0; r < 4; r++) {
      float v = fmaxf(acc[nf][r] + bcol, 0.f);
      lds_out[wid][lk * 4 + r][nf * 16 + lr] = (_Float16)v;
    }
  }
  __syncthreads();
#pragma unroll
  for (int it = 0; it < 2; it++) {
    int row_l = it * 8 + (lane >> 3);
    int col0 = (lane & 7) * 8;
    half8 v = *(const half8*)(&lds_out[wid][row_l][col0]);
    *(half8*)(out + (rowbase + row_l) * C + n0 + col0) = v;
  }
}

// ---------------- classifier: h2(f16) @ W_cls + b_cls -> f32 ----------------

__global__ __launch_bounds__(256) void classifier_k(const _Float16* __restrict__ h,
    const float* __restrict__ Wc, const float* __restrict__ bc, float* __restrict__ out) {
  __shared__ float Hs[64][C + 4];
  __shared__ float WcT[NCLS][C + 4];
  __shared__ float bs[NCLS];
  int tid = threadIdx.x;
  size_t row0 = (size_t)blockIdx.x * 64;
  for (int idx = tid; idx < C * NCLS; idx += 256) {
    int k = idx / NCLS, c = idx - k * NCLS;
    WcT[c][k] = Wc[idx];
  }
  if (tid < NCLS) bs[tid] = bc[tid];
  for (int f = tid; f < 64 * 16; f += 256) {
    int r = f >> 4, c8 = f & 15;
    size_t gr = row0 + r;
    if (gr < N_NODES) {
      half8 v = *(const half8*)(h + gr * C + c8 * 8);
#pragma unroll
      for (int q = 0; q < 8; q++) Hs[r][c8 * 8 + q] = (float)v[q];
    } else {
#pragma unroll
      for (int q = 0; q < 8; q++) Hs[r][c8 * 8 + q] = 0.f;
    }
  }
  __syncthreads();
  int r = tid >> 2, cg = tid & 3;
  float acc[10] = {};
#pragma unroll 2
  for (int k = 0; k < C; k += 4) {
    float4 a = *(const float4*)&Hs[r][k];
#pragma unroll
    for (int cc = 0; cc < 10; cc++) {
      float4 wv = *(const float4*)&WcT[cg * 10 + cc][k];
      acc[cc] += a.x * wv.x + a.y * wv.y + a.z * wv.z + a.w * wv.w;
    }
  }
  size_t gr = row0 + r;
  if (gr < N_NODES) {
#pragma unroll
    for (int cc = 0; cc < 10; cc++)
      out[gr * NCLS + cg * 10 + cc] = acc[cc] + bs[cg * 10 + cc];
  }
}

// ---------------- launch ----------------

extern "C" void kernel_launch(void* const* d_in, const int* in_sizes, int n_in,
                              void* d_out, int out_size, void* d_ws, size_t ws_size,
                              hipStream_t stream) {
  (void)in_sizes; (void)n_in; (void)out_size; (void)ws_size;
  const float* x   = (const float*)d_in[0];
  const int*   ei  = (const int*)d_in[1];
  const float* Ws1 = (const float*)d_in[2];
  const float* Wn1 = (const float*)d_in[3];
  const float* b1  = (const float*)d_in[4];
  const float* Ws2 = (const float*)d_in[5];
  const float* Wn2 = (const float*)d_in[6];
  const float* b2  = (const float*)d_in[7];
  const float* Wc  = (const float*)d_in[8];
  const float* bc  = (const float*)d_in[9];
  const int* src = ei;
  const int* dst = ei + N_EDGES;

  char* ws = (char*)d_ws;
  size_t off = 0;
  auto alloc = [&](size_t bytes) {
    void* p = ws + off;
    off = (off + bytes + 255) & ~(size_t)255;
    return p;
  };
  int*      deg      = (int*)alloc((size_t)N_NODES * 4);
  int*      rp       = (int*)alloc((size_t)(N_NODES + 1) * 4);
  int*      cursor   = (int*)alloc((size_t)N_NODES * 4);
  int*      partials = (int*)alloc(128 * 4);
  int*      pscan    = (int*)alloc(128 * 4);
  int*      csr      = (int*)alloc((size_t)N_EDGES * 4);
  _Float16* hA       = (_Float16*)alloc((size_t)N_NODES * C * 2);  // xh, later h2
  _Float16* hB       = (_Float16*)alloc((size_t)N_NODES * C * 2);  // agg outputs
  _Float16* hC       = (_Float16*)alloc((size_t)N_NODES * C * 2);  // h1
  _Float16* WT1      = (_Float16*)alloc((size_t)C * 256 * 2);
  _Float16* WT2      = (_Float16*)alloc((size_t)C * 256 * 2);
  float* outf = (float*)d_out;

  hipMemsetAsync(deg, 0, (size_t)N_NODES * 4, stream);
  deg_hist_k<<<(N_EDGES + 255) / 256, 256, 0, stream>>>(dst, deg);
  int nblk = (N_NODES + 1023) / 1024;  // 98
  scan_reduce_k<<<nblk, 256, 0, stream>>>(deg, partials);
  scan_partials_k<<<1, 64, 0, stream>>>(partials, pscan, nblk);
  scan_apply_k<<<nblk, 256, 0, stream>>>(deg, pscan, rp, cursor);
  scatter_k<<<(N_EDGES + 255) / 256, 256, 0, stream>>>(src, dst, cursor, csr);

  // weight prep + x conversion
  build_wt_k<<<C, 256, 0, stream>>>(Ws1, Wn1, WT1);
  build_wt_k<<<C, 256, 0, stream>>>(Ws2, Wn2, WT2);
  f32_to_f16_k<<<(N_NODES * C / 8 + 255) / 256, 256, 0, stream>>>(x, hA);

  // layer 1
  agg_mean_h_k<<<N_NODES / 4, 256, 0, stream>>>(hA, rp, csr, hB);
  sage_gemm_h_k<<<N_NODES / 32, 256, 0, stream>>>(hA, hB, WT1, b1, hC);
  // layer 2
  agg_mean_h_k<<<N_NODES / 4, 256, 0, stream>>>(hC, rp, csr, hB);
  sage_gemm_h_k<<<N_NODES / 32, 256, 0, stream>>>(hC, hB, WT2, b2, hA);
  // classifier
  classifier_k<<<(N_NODES + 63) / 64, 256, 0, stream>>>(hA, Wc, bc, outf);
}

// Round 3
// 418.111 us; speedup vs baseline: 2.1875x; 1.4688x over previous
//
#include <hip/hip_runtime.h>

#define N_NODES 100000
#define N_EDGES 1600000
#define C 128
#define NCLS 40
#define NBUCK 196   // ceil(100000/512)
#define BCAP 12288  // per-bucket edge capacity (mean 8163, sigma ~90)

typedef _Float16 half8 __attribute__((ext_vector_type(8)));
typedef float f32x4 __attribute__((ext_vector_type(4)));

// ================= bucketed CSR build =================
// Phase 1: scatter edges into 196 dst-buckets (512 nodes each), packed (src<<9)|loc.

__global__ __launch_bounds__(256) void bucket_scatter_k(const int* __restrict__ src,
    const int* __restrict__ dst, int* __restrict__ bucket_cnt, int* __restrict__ bucketArr) {
  __shared__ int lh[NBUCK], lbase[NBUCK], lcur[NBUCK];
  int tid = threadIdx.x;
  for (int i = tid; i < NBUCK; i += 256) { lh[i] = 0; lcur[i] = 0; }
  __syncthreads();
  int base = blockIdx.x * 4096;
  int bmax = min(base + 4096, N_EDGES);
  for (int e = base + tid; e < bmax; e += 256)
    atomicAdd(&lh[dst[e] >> 9], 1);
  __syncthreads();
  for (int i = tid; i < NBUCK; i += 256)
    lbase[i] = lh[i] ? atomicAdd(&bucket_cnt[i], lh[i]) : 0;
  __syncthreads();
  for (int e = base + tid; e < bmax; e += 256) {
    int d = dst[e];
    int b = d >> 9, loc = d & 511;
    int p = lbase[b] + atomicAdd(&lcur[b], 1);
    if (p < BCAP) bucketArr[(size_t)b * BCAP + p] = (src[e] << 9) | loc;
  }
}

// Small exclusive scan over bucket counts (196 entries) + rp[N] tail.
__global__ void bucket_scan_k(const int* __restrict__ bucket_cnt, int* __restrict__ bucket_base,
                              int* __restrict__ rp) {
  if (threadIdx.x == 0 && blockIdx.x == 0) {
    int run = 0;
    for (int b = 0; b < NBUCK; b++) {
      bucket_base[b] = run;
      run += min(bucket_cnt[b], BCAP);
    }
    bucket_base[NBUCK] = run;
    rp[N_NODES] = run;
  }
}

// Phase 2: one block per bucket; LDS counting-sort by local node; dense csr/rp writes.
__global__ __launch_bounds__(256) void bucket_sort_k(const int* __restrict__ bucketArr,
    const int* __restrict__ bucket_cnt, const int* __restrict__ bucket_base,
    int* __restrict__ rp, int* __restrict__ csr) {
  __shared__ int hist[512], offs[512], curs[512];
  __shared__ int wpart[4];
  __shared__ int lsrc[BCAP];
  int b = blockIdx.x, tid = threadIdx.x;
  int cnt = min(bucket_cnt[b], BCAP);
  int base = bucket_base[b];
  for (int i = tid; i < 512; i += 256) hist[i] = 0;
  __syncthreads();
  for (int i = tid; i < cnt; i += 256)
    atomicAdd(&hist[bucketArr[(size_t)b * BCAP + i] & 511], 1);
  __syncthreads();
  // block exclusive scan over 512 entries (2 per thread)
  int a0 = hist[2 * tid], a1 = hist[2 * tid + 1];
  int s = a0 + a1;
  int lane = tid & 63, wid = tid >> 6;
  int inc = s;
  for (int d = 1; d < 64; d <<= 1) { int y = __shfl_up(inc, d, 64); if (lane >= d) inc += y; }
  if (lane == 63) wpart[wid] = inc;
  __syncthreads();
  int woff = 0;
  for (int q = 0; q < wid; q++) woff += wpart[q];
  int ex = woff + inc - s;
  offs[2 * tid] = ex; offs[2 * tid + 1] = ex + a0;
  curs[2 * tid] = ex; curs[2 * tid + 1] = ex + a0;
  __syncthreads();
  for (int i = tid; i < 512; i += 256) {
    int gn = b * 512 + i;
    if (gn < N_NODES) rp[gn] = base + offs[i];
  }
  for (int i = tid; i < cnt; i += 256) {
    int packed = bucketArr[(size_t)b * BCAP + i];
    int p = atomicAdd(&curs[packed & 511], 1);
    lsrc[p] = packed >> 9;
  }
  __syncthreads();
  for (int i = tid; i < cnt; i += 256) csr[base + i] = lsrc[i];
}

// ================= fp32 -> fp16 convert / weight prep =================

__global__ __launch_bounds__(256) void f32_to_f16_k(const float* __restrict__ in,
                                                    _Float16* __restrict__ out) {
  int i = blockIdx.x * 256 + threadIdx.x;  // one thread = 8 elements
  float4 v0 = *(const float4*)(in + (size_t)i * 8);
  float4 v1 = *(const float4*)(in + (size_t)i * 8 + 4);
  half8 o;
  o[0] = (_Float16)v0.x; o[1] = (_Float16)v0.y; o[2] = (_Float16)v0.z; o[3] = (_Float16)v0.w;
  o[4] = (_Float16)v1.x; o[5] = (_Float16)v1.y; o[6] = (_Float16)v1.z; o[7] = (_Float16)v1.w;
  *(half8*)(out + (size_t)i * 8) = o;
}

// WT[n][k] = f16( k<128 ? Ws[k][n] : Wn[k-128][n] )
__global__ void build_wt_k(const float* __restrict__ Ws, const float* __restrict__ Wn,
                           _Float16* __restrict__ WT) {
  int n = blockIdx.x, k = threadIdx.x;
  float v = (k < 128) ? Ws[k * 128 + n] : Wn[(k - 128) * 128 + n];
  WT[n * 256 + k] = (_Float16)v;
}

// WcT[c][k] = f16(Wc[k][c]) padded to 48 cols; bcf padded f32 bias
__global__ void build_wct_k(const float* __restrict__ Wc, const float* __restrict__ bc,
                            _Float16* __restrict__ WcT, float* __restrict__ bcf) {
  int c = blockIdx.x, k = threadIdx.x;  // grid 48 x 128
  float v = (c < NCLS) ? Wc[k * NCLS + c] : 0.f;
  WcT[c * C + k] = (_Float16)v;
  if (k == 0) bcf[c] = (c < NCLS) ? bc[c] : 0.f;
}

// ================= mean aggregation =================
// wave = 1 node; 4 edges/iter (16 lanes x half8 = 16B/lane), unroll x2.

__global__ __launch_bounds__(256) void agg_mean_h_k(const _Float16* __restrict__ feat,
    const int* __restrict__ rp, const int* __restrict__ csr, _Float16* __restrict__ out) {
  int w = threadIdx.x >> 6;
  int node = blockIdx.x * 4 + w;
  int lane = threadIdx.x & 63;
  int g = lane >> 4, lr = lane & 15;
  int beg = rp[node], end = rp[node + 1];
  float acc[8] = {}, acc2[8] = {};
  int j = beg;
  for (; j + 8 <= end; j += 8) {
    int e0 = csr[j + g];
    int e1 = csr[j + 4 + g];
    half8 v0 = *(const half8*)(feat + (size_t)e0 * C + lr * 8);
    half8 v1 = *(const half8*)(feat + (size_t)e1 * C + lr * 8);
#pragma unroll
    for (int q = 0; q < 8; q++) { acc[q] += (float)v0[q]; acc2[q] += (float)v1[q]; }
  }
  for (; j + 4 <= end; j += 4) {
    int e0 = csr[j + g];
    half8 v0 = *(const half8*)(feat + (size_t)e0 * C + lr * 8);
#pragma unroll
    for (int q = 0; q < 8; q++) acc[q] += (float)v0[q];
  }
  int rem = end - j;
  if (g < rem) {
    int e0 = csr[j + g];
    half8 v0 = *(const half8*)(feat + (size_t)e0 * C + lr * 8);
#pragma unroll
    for (int q = 0; q < 8; q++) acc2[q] += (float)v0[q];
  }
#pragma unroll
  for (int q = 0; q < 8; q++) {
    float v = acc[q] + acc2[q];
    v += __shfl_xor(v, 16, 64);
    v += __shfl_xor(v, 32, 64);
    acc[q] = v;
  }
  if (g == 0) {
    float inv = 1.0f / fmaxf((float)(end - beg), 1.0f);
    half8 o;
#pragma unroll
    for (int q = 0; q < 8; q++) o[q] = (_Float16)(acc[q] * inv);
    *(half8*)(out + (size_t)node * C + lr * 8) = o;
  }
}

// ================= fused SAGE layer via MFMA f16 =================
// out = relu( [Xs|Xn] @ WT^T + b ), tile 32x128, 4 waves (2x2), wave tile 16x64.

__global__ __launch_bounds__(256) void sage_gemm_h_k(
    const _Float16* __restrict__ Xs, const _Float16* __restrict__ Xn,
    const _Float16* __restrict__ WT, const float* __restrict__ bias,
    _Float16* __restrict__ out) {
  __shared__ _Float16 lds_out[4][16][80];
  int tid = threadIdx.x;
  int lane = tid & 63, wid = tid >> 6;
  int wm = wid >> 1, wn = wid & 1;
  int lr = lane & 15, lk = lane >> 4;
  size_t rowbase = (size_t)blockIdx.x * 32 + wm * 16;
  int n0 = wn * 64;

  half8 a[8];
#pragma unroll
  for (int ks = 0; ks < 8; ks++) {
    const _Float16* Ap = (ks < 4)
        ? Xs + (rowbase + lr) * C + ks * 32 + lk * 8
        : Xn + (rowbase + lr) * C + (ks - 4) * 32 + lk * 8;
    a[ks] = *(const half8*)Ap;
  }

  f32x4 acc[4] = {};
#pragma unroll
  for (int ks = 0; ks < 8; ks++) {
#pragma unroll
    for (int nf = 0; nf < 4; nf++) {
      half8 b = *(const half8*)(WT + (size_t)(n0 + nf * 16 + lr) * 256 + ks * 32 + lk * 8);
      acc[nf] = __builtin_amdgcn_mfma_f32_16x16x32_f16(a[ks], b, acc[nf], 0, 0, 0);
    }
  }

#pragma unroll
  for (int nf = 0; nf < 4; nf++) {
    float bcol = bias[n0 + nf * 16 + lr];
#pragma unroll
    for (int r = 0; r < 4; r++) {
      float v = fmaxf(acc[nf][r] + bcol, 0.f);
      lds_out[wid][lk * 4 + r][nf * 16 + lr] = (_Float16)v;
    }
  }
  __syncthreads();
#pragma unroll
  for (int it = 0; it < 2; it++) {
    int row_l = it * 8 + (lane >> 3);
    int col0 = (lane & 7) * 8;
    half8 v = *(const half8*)(&lds_out[wid][row_l][col0]);
    *(half8*)(out + (rowbase + row_l) * C + n0 + col0) = v;
  }
}

// ================= classifier via MFMA: h2(f16) @ WcT^T + b -> f32 =================
// block 256 = 4 waves, 64 rows; wave tile 16 rows x 48 cols (3 frags), K=128.

__global__ __launch_bounds__(256) void classifier_mfma_k(const _Float16* __restrict__ h,
    const _Float16* __restrict__ WcT, const float* __restrict__ bcf, float* __restrict__ out) {
  __shared__ float cbuf[64][49];
  int tid = threadIdx.x, lane = tid & 63, wid = tid >> 6;
  int lr = lane & 15, lk = lane >> 4;
  int row0 = blockIdx.x * 64 + wid * 16;
  f32x4 acc[3] = {};
#pragma unroll
  for (int ks = 0; ks < 4; ks++) {
    half8 a = {};
    int r = row0 + lr;
    if (r < N_NODES) a = *(const half8*)(h + (size_t)r * C + ks * 32 + lk * 8);
#pragma unroll
    for (int nf = 0; nf < 3; nf++) {
      half8 bfr = *(const half8*)(WcT + (size_t)(nf * 16 + lr) * C + ks * 32 + lk * 8);
      acc[nf] = __builtin_amdgcn_mfma_f32_16x16x32_f16(a, bfr, acc[nf], 0, 0, 0);
    }
  }
#pragma unroll
  for (int nf = 0; nf < 3; nf++)
#pragma unroll
    for (int q = 0; q < 4; q++) {
      int c = nf * 16 + lr;
      cbuf[wid * 16 + lk * 4 + q][c] = acc[nf][q] + bcf[c];
    }
  __syncthreads();
  int row_blk0 = blockIdx.x * 64;
  for (int i = tid; i < 64 * NCLS; i += 256) {
    int r = i / NCLS, c = i - r * NCLS;
    int gr = row_blk0 + r;
    if (gr < N_NODES) out[(size_t)gr * NCLS + c] = cbuf[r][c];
  }
}

// ================= launch =================

extern "C" void kernel_launch(void* const* d_in, const int* in_sizes, int n_in,
                              void* d_out, int out_size, void* d_ws, size_t ws_size,
                              hipStream_t stream) {
  (void)in_sizes; (void)n_in; (void)out_size; (void)ws_size;
  const float* x   = (const float*)d_in[0];
  const int*   ei  = (const int*)d_in[1];
  const float* Ws1 = (const float*)d_in[2];
  const float* Wn1 = (const float*)d_in[3];
  const float* b1  = (const float*)d_in[4];
  const float* Ws2 = (const float*)d_in[5];
  const float* Wn2 = (const float*)d_in[6];
  const float* b2  = (const float*)d_in[7];
  const float* Wc  = (const float*)d_in[8];
  const float* bc  = (const float*)d_in[9];
  const int* src = ei;
  const int* dst = ei + N_EDGES;

  char* ws = (char*)d_ws;
  size_t off = 0;
  auto alloc = [&](size_t bytes) {
    void* p = ws + off;
    off = (off + bytes + 255) & ~(size_t)255;
    return p;
  };
  int*      bucket_cnt  = (int*)alloc((size_t)NBUCK * 4);
  int*      bucket_base = (int*)alloc((size_t)(NBUCK + 1) * 4);
  int*      bucketArr   = (int*)alloc((size_t)NBUCK * BCAP * 4);
  int*      rp          = (int*)alloc((size_t)(N_NODES + 1) * 4);
  int*      csr         = (int*)alloc((size_t)N_EDGES * 4);
  _Float16* hA          = (_Float16*)alloc((size_t)N_NODES * C * 2);  // x_h, later h2
  _Float16* hB          = (_Float16*)alloc((size_t)N_NODES * C * 2);  // agg outputs
  _Float16* hC          = (_Float16*)alloc((size_t)N_NODES * C * 2);  // h1
  _Float16* WT1         = (_Float16*)alloc((size_t)C * 256 * 2);
  _Float16* WT2         = (_Float16*)alloc((size_t)C * 256 * 2);
  _Float16* WcT         = (_Float16*)alloc((size_t)48 * C * 2);
  float*    bcf         = (float*)alloc(48 * 4);
  float* outf = (float*)d_out;

  // CSR build (bucketed counting sort)
  hipMemsetAsync(bucket_cnt, 0, (size_t)NBUCK * 4, stream);
  bucket_scatter_k<<<(N_EDGES + 4095) / 4096, 256, 0, stream>>>(src, dst, bucket_cnt, bucketArr);
  bucket_scan_k<<<1, 64, 0, stream>>>(bucket_cnt, bucket_base, rp);
  bucket_sort_k<<<NBUCK, 256, 0, stream>>>(bucketArr, bucket_cnt, bucket_base, rp, csr);

  // weight prep + x conversion
  build_wt_k<<<C, 256, 0, stream>>>(Ws1, Wn1, WT1);
  build_wt_k<<<C, 256, 0, stream>>>(Ws2, Wn2, WT2);
  build_wct_k<<<48, C, 0, stream>>>(Wc, bc, WcT, bcf);
  f32_to_f16_k<<<(N_NODES * C / 8) / 256, 256, 0, stream>>>(x, hA);

  // layer 1
  agg_mean_h_k<<<N_NODES / 4, 256, 0, stream>>>(hA, rp, csr, hB);
  sage_gemm_h_k<<<N_NODES / 32, 256, 0, stream>>>(hA, hB, WT1, b1, hC);
  // layer 2
  agg_mean_h_k<<<N_NODES / 4, 256, 0, stream>>>(hC, rp, csr, hB);
  sage_gemm_h_k<<<N_NODES / 32, 256, 0, stream>>>(hC, hB, WT2, b2, hA);
  // classifier
  classifier_mfma_k<<<(N_NODES + 63) / 64, 256, 0, stream>>>(hA, WcT, bcf, outf);
}

// Round 4
// 371.835 us; speedup vs baseline: 2.4597x; 1.1245x over previous
//
#include <hip/hip_runtime.h>

#define N_NODES 100000
#define N_EDGES 1600000
#define C 128
#define NCLS 40
#define NBUCK 196   // ceil(100000/512)
#define BCAP 12288  // per-bucket edge capacity (mean 8163, sigma ~90)
#define NT_TILES 3125  // 100000/32

typedef _Float16 half8 __attribute__((ext_vector_type(8)));
typedef float f32x4 __attribute__((ext_vector_type(4)));
typedef float f32x16 __attribute__((ext_vector_type(16)));

// ================= bucketed CSR build =================

__global__ __launch_bounds__(256) void bucket_scatter_k(const int* __restrict__ src,
    const int* __restrict__ dst, int* __restrict__ bucket_cnt, int* __restrict__ bucketArr) {
  __shared__ int lh[NBUCK], lbase[NBUCK], lcur[NBUCK];
  int tid = threadIdx.x;
  for (int i = tid; i < NBUCK; i += 256) { lh[i] = 0; lcur[i] = 0; }
  __syncthreads();
  int base = blockIdx.x * 4096;
  int bmax = min(base + 4096, N_EDGES);
  for (int e = base + tid; e < bmax; e += 256)
    atomicAdd(&lh[dst[e] >> 9], 1);
  __syncthreads();
  for (int i = tid; i < NBUCK; i += 256)
    lbase[i] = lh[i] ? atomicAdd(&bucket_cnt[i], lh[i]) : 0;
  __syncthreads();
  for (int e = base + tid; e < bmax; e += 256) {
    int d = dst[e];
    int b = d >> 9, loc = d & 511;
    int p = lbase[b] + atomicAdd(&lcur[b], 1);
    if (p < BCAP) bucketArr[(size_t)b * BCAP + p] = (src[e] << 9) | loc;
  }
}

__global__ void bucket_scan_k(const int* __restrict__ bucket_cnt, int* __restrict__ bucket_base,
                              int* __restrict__ rp) {
  if (threadIdx.x == 0 && blockIdx.x == 0) {
    int run = 0;
    for (int b = 0; b < NBUCK; b++) {
      bucket_base[b] = run;
      run += min(bucket_cnt[b], BCAP);
    }
    bucket_base[NBUCK] = run;
    rp[N_NODES] = run;
  }
}

__global__ __launch_bounds__(256) void bucket_sort_k(const int* __restrict__ bucketArr,
    const int* __restrict__ bucket_cnt, const int* __restrict__ bucket_base,
    int* __restrict__ rp, int* __restrict__ csr) {
  __shared__ int hist[512], offs[512], curs[512];
  __shared__ int wpart[4];
  __shared__ int lsrc[BCAP];
  int b = blockIdx.x, tid = threadIdx.x;
  int cnt = min(bucket_cnt[b], BCAP);
  int base = bucket_base[b];
  for (int i = tid; i < 512; i += 256) hist[i] = 0;
  __syncthreads();
  for (int i = tid; i < cnt; i += 256)
    atomicAdd(&hist[bucketArr[(size_t)b * BCAP + i] & 511], 1);
  __syncthreads();
  int a0 = hist[2 * tid], a1 = hist[2 * tid + 1];
  int s = a0 + a1;
  int lane = tid & 63, wid = tid >> 6;
  int inc = s;
  for (int d = 1; d < 64; d <<= 1) { int y = __shfl_up(inc, d, 64); if (lane >= d) inc += y; }
  if (lane == 63) wpart[wid] = inc;
  __syncthreads();
  int woff = 0;
  for (int q = 0; q < wid; q++) woff += wpart[q];
  int ex = woff + inc - s;
  offs[2 * tid] = ex; offs[2 * tid + 1] = ex + a0;
  curs[2 * tid] = ex; curs[2 * tid + 1] = ex + a0;
  __syncthreads();
  for (int i = tid; i < 512; i += 256) {
    int gn = b * 512 + i;
    if (gn < N_NODES) rp[gn] = base + offs[i];
  }
  for (int i = tid; i < cnt; i += 256) {
    int packed = bucketArr[(size_t)b * BCAP + i];
    int p = atomicAdd(&curs[packed & 511], 1);
    lsrc[p] = packed >> 9;
  }
  __syncthreads();
  for (int i = tid; i < cnt; i += 256) csr[base + i] = lsrc[i];
}

// ================= fp32 -> fp16 convert / weight prep =================

__global__ __launch_bounds__(256) void f32_to_f16_k(const float* __restrict__ in,
                                                    _Float16* __restrict__ out) {
  int i = blockIdx.x * 256 + threadIdx.x;
  float4 v0 = *(const float4*)(in + (size_t)i * 8);
  float4 v1 = *(const float4*)(in + (size_t)i * 8 + 4);
  half8 o;
  o[0] = (_Float16)v0.x; o[1] = (_Float16)v0.y; o[2] = (_Float16)v0.z; o[3] = (_Float16)v0.w;
  o[4] = (_Float16)v1.x; o[5] = (_Float16)v1.y; o[6] = (_Float16)v1.z; o[7] = (_Float16)v1.w;
  *(half8*)(out + (size_t)i * 8) = o;
}

// WT[n][k] = f16( k<128 ? Ws[k][n] : Wn[k-128][n] )
__global__ void build_wt_k(const float* __restrict__ Ws, const float* __restrict__ Wn,
                           _Float16* __restrict__ WT) {
  int n = blockIdx.x, k = threadIdx.x;
  float v = (k < 128) ? Ws[k * 128 + n] : Wn[(k - 128) * 128 + n];
  WT[n * 256 + k] = (_Float16)v;
}

__global__ void build_wct_k(const float* __restrict__ Wc, const float* __restrict__ bc,
                            _Float16* __restrict__ WcT, float* __restrict__ bcf) {
  int c = blockIdx.x, k = threadIdx.x;
  float v = (c < NCLS) ? Wc[k * NCLS + c] : 0.f;
  WcT[c * C + k] = (_Float16)v;
  if (k == 0) bcf[c] = (c < NCLS) ? bc[c] : 0.f;
}

// ================= mean aggregation =================

__global__ __launch_bounds__(256) void agg_mean_h_k(const _Float16* __restrict__ feat,
    const int* __restrict__ rp, const int* __restrict__ csr, _Float16* __restrict__ out) {
  int w = threadIdx.x >> 6;
  int node = blockIdx.x * 4 + w;
  int lane = threadIdx.x & 63;
  int g = lane >> 4, lr = lane & 15;
  int beg = rp[node], end = rp[node + 1];
  float acc[8] = {}, acc2[8] = {};
  int j = beg;
  for (; j + 8 <= end; j += 8) {
    int e0 = csr[j + g];
    int e1 = csr[j + 4 + g];
    half8 v0 = *(const half8*)(feat + (size_t)e0 * C + lr * 8);
    half8 v1 = *(const half8*)(feat + (size_t)e1 * C + lr * 8);
#pragma unroll
    for (int q = 0; q < 8; q++) { acc[q] += (float)v0[q]; acc2[q] += (float)v1[q]; }
  }
  for (; j + 4 <= end; j += 4) {
    int e0 = csr[j + g];
    half8 v0 = *(const half8*)(feat + (size_t)e0 * C + lr * 8);
#pragma unroll
    for (int q = 0; q < 8; q++) acc[q] += (float)v0[q];
  }
  int rem = end - j;
  if (g < rem) {
    int e0 = csr[j + g];
    half8 v0 = *(const half8*)(feat + (size_t)e0 * C + lr * 8);
#pragma unroll
    for (int q = 0; q < 8; q++) acc2[q] += (float)v0[q];
  }
#pragma unroll
  for (int q = 0; q < 8; q++) {
    float v = acc[q] + acc2[q];
    v += __shfl_xor(v, 16, 64);
    v += __shfl_xor(v, 32, 64);
    acc[q] = v;
  }
  if (g == 0) {
    float inv = 1.0f / fmaxf((float)(end - beg), 1.0f);
    half8 o;
#pragma unroll
    for (int q = 0; q < 8; q++) o[q] = (_Float16)(acc[q] * inv);
    *(half8*)(out + (size_t)node * C + lr * 8) = o;
  }
}

// ================= weights-stationary fused SAGE GEMM =================
// out = relu( [Xs|Xn] @ WT^T + b ).  Wave = fixed 32-col slice, B frags in
// registers for the block's whole lifetime; grid-stride over 32-row tiles.
// MFMA 32x32x16 f16: A row=lane&31 k=(lane>>5)*8+j; B col=lane&31 same k;
// C/D col=lane&31, row=(q&3)+8*(q>>2)+4*(lane>>5)  [m74/m101 verified].

__global__ __launch_bounds__(256) void sage_gemm_ws_k(
    const _Float16* __restrict__ Xs, const _Float16* __restrict__ Xn,
    const _Float16* __restrict__ WT, const float* __restrict__ bias,
    _Float16* __restrict__ out) {
  __shared__ _Float16 cbuf[32][136];  // 272B row stride: epilogue write conflict-free
  int tid = threadIdx.x, lane = tid & 63, wid = tid >> 6;
  int l31 = lane & 31, l5 = lane >> 5;
  int col0 = wid * 32;

  half8 b[16];
#pragma unroll
  for (int ks = 0; ks < 16; ks++)
    b[ks] = *(const half8*)(WT + (size_t)(col0 + l31) * 256 + ks * 16 + l5 * 8);
  float bcol = bias[col0 + l31];

  for (int t = blockIdx.x; t < NT_TILES; t += gridDim.x) {
    size_t row0 = (size_t)t * 32;
    half8 a[16];
#pragma unroll
    for (int ks = 0; ks < 8; ks++) {
      a[ks]     = *(const half8*)(Xs + (row0 + l31) * C + ks * 16 + l5 * 8);
      a[ks + 8] = *(const half8*)(Xn + (row0 + l31) * C + ks * 16 + l5 * 8);
    }
    f32x16 acc = {};
#pragma unroll
    for (int ks = 0; ks < 16; ks++)
      acc = __builtin_amdgcn_mfma_f32_32x32x16_f16(a[ks], b[ks], acc, 0, 0, 0);

    __syncthreads();  // cbuf reuse guard (prev iteration's readers done)
#pragma unroll
    for (int q = 0; q < 16; q++) {
      int row = (q & 3) + 8 * (q >> 2) + 4 * l5;
      float v = fmaxf(acc[q] + bcol, 0.f);
      cbuf[row][col0 + l31] = (_Float16)v;
    }
    __syncthreads();
#pragma unroll
    for (int p = 0; p < 2; p++) {
      int chunk = tid + p * 256;         // 512 chunks of half8
      int r = chunk >> 4, cg = chunk & 15;
      half8 v = *(const half8*)&cbuf[r][cg * 8];
      *(half8*)(out + (row0 + r) * C + cg * 8) = v;
    }
  }
}

// ================= classifier via MFMA =================

__global__ __launch_bounds__(256) void classifier_mfma_k(const _Float16* __restrict__ h,
    const _Float16* __restrict__ WcT, const float* __restrict__ bcf, float* __restrict__ out) {
  __shared__ float cbuf[64][49];
  int tid = threadIdx.x, lane = tid & 63, wid = tid >> 6;
  int lr = lane & 15, lk = lane >> 4;
  int row0 = blockIdx.x * 64 + wid * 16;
  f32x4 acc[3] = {};
#pragma unroll
  for (int ks = 0; ks < 4; ks++) {
    half8 a = {};
    int r = row0 + lr;
    if (r < N_NODES) a = *(const half8*)(h + (size_t)r * C + ks * 32 + lk * 8);
#pragma unroll
    for (int nf = 0; nf < 3; nf++) {
      half8 bfr = *(const half8*)(WcT + (size_t)(nf * 16 + lr) * C + ks * 32 + lk * 8);
      acc[nf] = __builtin_amdgcn_mfma_f32_16x16x32_f16(a, bfr, acc[nf], 0, 0, 0);
    }
  }
#pragma unroll
  for (int nf = 0; nf < 3; nf++)
#pragma unroll
    for (int q = 0; q < 4; q++) {
      int c = nf * 16 + lr;
      cbuf[wid * 16 + lk * 4 + q][c] = acc[nf][q] + bcf[c];
    }
  __syncthreads();
  int row_blk0 = blockIdx.x * 64;
  for (int i = tid; i < 64 * NCLS; i += 256) {
    int r = i / NCLS, c = i - r * NCLS;
    int gr = row_blk0 + r;
    if (gr < N_NODES) out[(size_t)gr * NCLS + c] = cbuf[r][c];
  }
}

// ================= launch =================

extern "C" void kernel_launch(void* const* d_in, const int* in_sizes, int n_in,
                              void* d_out, int out_size, void* d_ws, size_t ws_size,
                              hipStream_t stream) {
  (void)in_sizes; (void)n_in; (void)out_size; (void)ws_size;
  const float* x   = (const float*)d_in[0];
  const int*   ei  = (const int*)d_in[1];
  const float* Ws1 = (const float*)d_in[2];
  const float* Wn1 = (const float*)d_in[3];
  const float* b1  = (const float*)d_in[4];
  const float* Ws2 = (const float*)d_in[5];
  const float* Wn2 = (const float*)d_in[6];
  const float* b2  = (const float*)d_in[7];
  const float* Wc  = (const float*)d_in[8];
  const float* bc  = (const float*)d_in[9];
  const int* src = ei;
  const int* dst = ei + N_EDGES;

  char* ws = (char*)d_ws;
  size_t off = 0;
  auto alloc = [&](size_t bytes) {
    void* p = ws + off;
    off = (off + bytes + 255) & ~(size_t)255;
    return p;
  };
  int*      bucket_cnt  = (int*)alloc((size_t)NBUCK * 4);
  int*      bucket_base = (int*)alloc((size_t)(NBUCK + 1) * 4);
  int*      bucketArr   = (int*)alloc((size_t)NBUCK * BCAP * 4);
  int*      rp          = (int*)alloc((size_t)(N_NODES + 1) * 4);
  int*      csr         = (int*)alloc((size_t)N_EDGES * 4);
  _Float16* hA          = (_Float16*)alloc((size_t)N_NODES * C * 2);
  _Float16* hB          = (_Float16*)alloc((size_t)N_NODES * C * 2);
  _Float16* hC          = (_Float16*)alloc((size_t)N_NODES * C * 2);
  _Float16* WT1         = (_Float16*)alloc((size_t)C * 256 * 2);
  _Float16* WT2         = (_Float16*)alloc((size_t)C * 256 * 2);
  _Float16* WcT         = (_Float16*)alloc((size_t)48 * C * 2);
  float*    bcf         = (float*)alloc(48 * 4);
  float* outf = (float*)d_out;

  hipMemsetAsync(bucket_cnt, 0, (size_t)NBUCK * 4, stream);
  bucket_scatter_k<<<(N_EDGES + 4095) / 4096, 256, 0, stream>>>(src, dst, bucket_cnt, bucketArr);
  bucket_scan_k<<<1, 64, 0, stream>>>(bucket_cnt, bucket_base, rp);
  bucket_sort_k<<<NBUCK, 256, 0, stream>>>(bucketArr, bucket_cnt, bucket_base, rp, csr);

  build_wt_k<<<C, 256, 0, stream>>>(Ws1, Wn1, WT1);
  build_wt_k<<<C, 256, 0, stream>>>(Ws2, Wn2, WT2);
  build_wct_k<<<48, C, 0, stream>>>(Wc, bc, WcT, bcf);
  f32_to_f16_k<<<(N_NODES * C / 8) / 256, 256, 0, stream>>>(x, hA);

  // layer 1
  agg_mean_h_k<<<N_NODES / 4, 256, 0, stream>>>(hA, rp, csr, hB);
  sage_gemm_ws_k<<<782, 256, 0, stream>>>(hA, hB, WT1, b1, hC);
  // layer 2
  agg_mean_h_k<<<N_NODES / 4, 256, 0, stream>>>(hC, rp, csr, hB);
  sage_gemm_ws_k<<<782, 256, 0, stream>>>(hC, hB, WT2, b2, hA);
  // classifier
  classifier_mfma_k<<<(N_NODES + 63) / 64, 256, 0, stream>>>(hA, WcT, bcf, outf);
}